// Round 3
// baseline (48.081 us; speedup 1.0000x reference)
//
#include <hip/hip_runtime.h>
#include <hip/hip_bf16.h>
#include <math.h>

#define HDIM 150

typedef __bf16 bf16x8 __attribute__((ext_vector_type(8)));
typedef __bf16 bf16x4 __attribute__((ext_vector_type(4)));
typedef float  f32x4  __attribute__((ext_vector_type(4)));

__device__ __forceinline__ void async_copy16(const void* g, void* l) {
    __builtin_amdgcn_global_load_lds(
        (const __attribute__((address_space(1))) void*)g,
        (__attribute__((address_space(3))) void*)l, 16, 0, 0);
}

// ---------------------------------------------------------------------------
// k_pack: one block precomputes every per-lane MFMA fragment blob.
// Blob layout (uint4 view): tile i of lane L at blob4[i*64 + L].
//   tiles 0..9  : layer1 A-fragments (consumed from LDS by k_fused)
//   tiles 10..14: layer2 A-fragments; tile 15: b2
//   tiles 16..35: head A-fragments  tile 16 + jt*2 + kc  =
//                 A[row = jt*16+m][k = kc*32+q*8+j] = W3[k][jt*16+m] (bf16)
// ---------------------------------------------------------------------------
__global__ void k_pack(const float* __restrict__ W1, const float* __restrict__ b1,
                       const float* __restrict__ W2, const float* __restrict__ b2,
                       const float* __restrict__ W3,
                       unsigned int* __restrict__ blob)
{
    __shared__ float sW[6000];   // phase1: W1|b1@2700|W2@2850 ; phase2: W3[40][150]

    const int t    = threadIdx.x;
    const int lane = t & 63;
    const int c    = t >> 6;        // dword chunk 0..3
    const int m    = lane & 15;
    const int q    = lane >> 4;

    for (int e = t; e < 2700; e += 256) sW[e] = W1[e];
    for (int e = t; e < 150;  e += 256) sW[2700 + e] = b1[e];
    for (int e = t; e < 1200; e += 256) sW[2850 + e] = W2[e];
    __syncthreads();

    for (int d = c * 16; d < c * 16 + 16; ++d) {
        unsigned int word;
        if (d >= 60) {
            word = __float_as_uint(b2[(q & 1) * 4 + (d - 60)]);
        } else {
            float v0 = 0.f, v1 = 0.f;
            if (d < 40) {
                int n = d >> 2, j0 = (d & 3) * 2;
                // permuted hidden rows for the register relay:
                //   tile 2kt   row(4q+r) = hidden 32kt+8q+r
                //   tile 2kt+1 row(4q+r) = hidden 32kt+8q+4+r
                int hid = 32 * (n >> 1) + 8 * (m >> 2) + 4 * (n & 1) + (m & 3);
                if (hid < HDIM) {
                    int k0 = q * 8 + j0, k1 = k0 + 1;
                    v0 = (k0 < 18) ? sW[k0 * HDIM + hid] : (k0 == 18 ? sW[2700 + hid] : 0.f);
                    v1 = (k1 < 18) ? sW[k1 * HDIM + hid] : (k1 == 18 ? sW[2700 + hid] : 0.f);
                }
            } else {
                int kt = (d - 40) >> 2, j0 = ((d - 40) & 3) * 2;
                int k0 = kt * 32 + q * 8 + j0, k1 = k0 + 1;
                if (m < 8) {
                    v0 = (k0 < HDIM) ? sW[2850 + k0 * 8 + m] : 0.f;
                    v1 = (k1 < HDIM) ? sW[2850 + k1 * 8 + m] : 0.f;
                }
            }
            __bf16 h0 = (__bf16)v0, h1 = (__bf16)v1;
            unsigned short u0, u1;
            __builtin_memcpy(&u0, &h0, 2);
            __builtin_memcpy(&u1, &h1, 2);
            word = (unsigned int)u0 | ((unsigned int)u1 << 16);
        }
        blob[(d >> 2) * 256 + lane * 4 + (d & 3)] = word;
    }
    __syncthreads();   // phase-1 reads of sW complete

    // ---- head A-fragments from W3 [40][150] row-major ----
    for (int e = t; e < 6000; e += 256) sW[e] = W3[e];
    __syncthreads();

    for (int f = t; f < 20 * 256; f += 256) {
        int tile  = f >> 8, rem = f & 255;
        int lane2 = rem >> 2, dw = rem & 3;
        int m2 = lane2 & 15, q2 = lane2 >> 4;
        int jt = tile >> 1, kc = tile & 1;
        int row = jt * 16 + m2;
        int k0  = kc * 32 + q2 * 8 + dw * 2;
        float v0 = (k0     < 40 && row < HDIM) ? sW[k0 * HDIM + row] : 0.f;
        float v1 = (k0 + 1 < 40 && row < HDIM) ? sW[(k0 + 1) * HDIM + row] : 0.f;
        __bf16 h0 = (__bf16)v0, h1 = (__bf16)v1;
        unsigned short u0, u1;
        __builtin_memcpy(&u0, &h0, 2);
        __builtin_memcpy(&u1, &h1, 2);
        blob[(16 + tile) * 256 + lane2 * 4 + dw] =
            (unsigned int)u0 | ((unsigned int)u1 << 16);
    }
}

// ---------------------------------------------------------------------------
// fully unrolled Batcher odd-even mergesort, n = 16
// ---------------------------------------------------------------------------
__device__ __forceinline__ void cswap(float& a, float& b) {
    float lo = fminf(a, b);
    float hi = fmaxf(a, b);
    a = lo; b = hi;
}

__device__ __forceinline__ void sort16(float v[16]) {
#pragma unroll
    for (int pp = 1; pp < 16; pp <<= 1) {
#pragma unroll
        for (int k = pp; k >= 1; k >>= 1) {
#pragma unroll
            for (int j = k & (pp - 1); j + k < 16; j += 2 * k) {
#pragma unroll
                for (int i = 0; i < k; ++i) {
                    if ((i + j) / (2 * pp) == (i + j + k) / (2 * pp))
                        cswap(v[i + j], v[i + j + k]);
                }
            }
        }
    }
}

// ---------------------------------------------------------------------------
// k_fused R11: occupancy-first restructure.
// Block = 256 threads = 16 sites = 512 reads (grid 2048).
//  * layer1 A-fragments live in LDS (10KB, staged once per block, shared by
//    all waves) -> unified reg footprint drops ~40 -> __launch_bounds__(256,6)
//  * ring = 2 x 1KB per wave (1-tile double buffer, vmcnt(1) pipelining)
//  * LDS total 26.6KB -> 6 blocks/CU = 24 waves/CU (75% occupancy)
//  * agg: 16 threads/site (2 halves x 8 ch); sort16 per thread + bitonic
//    median-of-32 merge via shfl_xor(8): max_i min(a[i], b[15-i]); min/max
//    free from sorted halves. No barrier between MLP and agg (each wave
//    aggregates exactly the sites it produced).
// LDS map: [0,8K) 4 wave rings (post-MLP: AggW(wv)@wv*2048, sB3/sW4 in
// ring3, sPart in ring0 tail); [8K,16K) sH (16 x 512B, XOR-by-site swizzle);
// [16K,26.6K) layer1 fragment tiles.
// ---------------------------------------------------------------------------
#define RING_B     2048
#define SH_OFF     8192
#define BLOBL_OFF  16384
#define SB3_OFF    6848     // ring3 + 704
#define SW4_OFF    7488     // ring3 + 1344
#define SPART_OFF  1792     // ring0 tail
#define SMEM_TOTAL 26624

__global__ __launch_bounds__(256, 6) void k_fused(
    const float* __restrict__ x, const int* __restrict__ kmer,
    const int* __restrict__ indices, const float* __restrict__ emb,
    const unsigned int* __restrict__ blob,
    const float* __restrict__ b3, const float* __restrict__ W4,
    const float* __restrict__ b4,
    float* __restrict__ out, int Gtot)
{
    __shared__ __align__(16) char smem[SMEM_TOTAL];

    const int tid  = threadIdx.x;
    const int lane = tid & 63;
    const int wv   = tid >> 6;
    const int m    = lane & 15;
    const int q    = lane >> 4;

    const uint4* bl = (const uint4*)blob;

    // ---- stage layer1 fragments (tiles 0..9) into LDS via DMA ----
    for (int i = wv; i < 10; i += 4)
        async_copy16((const char*)blob + i * 1024 + lane * 16,
                     smem + BLOBL_OFF + i * 1024);

    // ---- layer2 fragments + b2 stay in registers (6 uint4) ----
    uint4 B16[6];
#pragma unroll
    for (int i = 0; i < 6; ++i) B16[i] = bl[(10 + i) * 64 + lane];
    const bf16x8* fr2 = (const bf16x8*)B16;      // fr2[0..4] = layer2 frags
    const float4 breg = ((const float4*)B16)[5];

    const int gblk  = blockIdx.x * 16;           // first site of this block
    const int rbase = gblk * 32;                 // first flat read-slot

    int    rg[2];
    float2 eg[2];
    {
        const int lim = Gtot * 32 - 1;
#pragma unroll
        for (int g = 0; g < 2; ++g) {
            int fl = rbase + wv * 128 + g * 64 + lane;
            rg[g] = indices[fl > lim ? lim : fl];
        }
        int kk[2];
#pragma unroll
        for (int g = 0; g < 2; ++g) kk[g] = kmer[rg[g]];
        const float2* emb2 = (const float2*)emb;
#pragma unroll
        for (int g = 0; g < 2; ++g) eg[g] = emb2[kk[g]];
    }

    char* xb = smem + wv * RING_B;
    const char* xg = (const char*)x;
    const int gsw = lane ^ ((lane >> 3) & 7);    // swizzled granule for DMA
    const int rsl = gsw >> 2;                    // read slot in tile (0..15)
    const int rch = gsw & 3;                     // 16B chunk in x row

    // x tile 0 into buffer 0 (drained by the barrier below)
    {
        int rr = __shfl(rg[0], rsl);
        async_copy16(xg + (size_t)rr * 64 + (size_t)rch * 16, xb);
    }
    __syncthreads();   // fragment tiles staged; all DMA drained

    __bf16* sH = (__bf16*)(smem + SH_OFF);
    const char* fA1 = smem + BLOBL_OFF;
    const f32x4 zero = {0.f, 0.f, 0.f, 0.f};

#pragma unroll
    for (int t = 0; t < 8; ++t) {
        // prefetch next 1KB tile into the other buffer; counted wait keeps it
        // in flight while we compute this tile
        if (t < 7) {
            int t1 = t + 1;
            int rr = __shfl(rg[t1 >> 2], ((t1 & 3) << 4) + rsl);
            async_copy16(xg + (size_t)rr * 64 + (size_t)rch * 16,
                         xb + ((t1 & 1) << 10));
            asm volatile("s_waitcnt vmcnt(1)" ::: "memory");
        } else {
            asm volatile("s_waitcnt vmcnt(0)" ::: "memory");
        }

        float ex = __shfl(eg[t >> 2].x, ((t & 3) << 4) + m);
        float ey = __shfl(eg[t >> 2].y, ((t & 3) << 4) + m);

        // input B-fragment: B[k = q*8+j][n = read m]
        bf16x8 bin;
        if (q < 2) {
            int g0 = 4 * m + 2 * q;
            int sx = (g0 >> 3) & 7;
            const char* tb = xb + ((t & 1) << 10);
            f32x4 u0 = *(const f32x4*)(tb + ((g0       ^ sx) << 4));
            f32x4 u1 = *(const f32x4*)(tb + (((g0 + 1) ^ sx) << 4));
            bin[0] = (__bf16)u0[0]; bin[1] = (__bf16)u0[1];
            bin[2] = (__bf16)u0[2]; bin[3] = (__bf16)u0[3];
            bin[4] = (__bf16)u1[0]; bin[5] = (__bf16)u1[1];
            bin[6] = (__bf16)u1[2]; bin[7] = (__bf16)u1[3];
        } else if (q == 2) {
            bin[0] = (__bf16)ex; bin[1] = (__bf16)ey;
            bin[2] = (__bf16)1.0f;   // bias-1 input at k==18
            bin[3] = (__bf16)0.f; bin[4] = (__bf16)0.f;
            bin[5] = (__bf16)0.f; bin[6] = (__bf16)0.f; bin[7] = (__bf16)0.f;
        } else {
#pragma unroll
            for (int j = 0; j < 8; ++j) bin[j] = (__bf16)0.f;
        }

        // layer1 (A-frags from LDS) -> relu/pack -> layer2 (reg frags)
        f32x4 c2a = zero, c2b = zero;
#pragma unroll
        for (int kt = 0; kt < 5; ++kt) {
            bf16x8 fa = *(const bf16x8*)(fA1 + (2 * kt)     * 1024 + lane * 16);
            bf16x8 fb = *(const bf16x8*)(fA1 + (2 * kt + 1) * 1024 + lane * 16);
            f32x4 ca = __builtin_amdgcn_mfma_f32_16x16x32_bf16(fa, bin, zero, 0, 0, 0);
            f32x4 cb = __builtin_amdgcn_mfma_f32_16x16x32_bf16(fb, bin, zero, 0, 0, 0);
            bf16x8 bh;
            bh[0] = (__bf16)fmaxf(ca[0], 0.f); bh[1] = (__bf16)fmaxf(ca[1], 0.f);
            bh[2] = (__bf16)fmaxf(ca[2], 0.f); bh[3] = (__bf16)fmaxf(ca[3], 0.f);
            bh[4] = (__bf16)fmaxf(cb[0], 0.f); bh[5] = (__bf16)fmaxf(cb[1], 0.f);
            bh[6] = (__bf16)fmaxf(cb[2], 0.f); bh[7] = (__bf16)fmaxf(cb[3], 0.f);
            if (kt & 1) c2b = __builtin_amdgcn_mfma_f32_16x16x32_bf16(fr2[kt], bh, c2b, 0, 0, 0);
            else        c2a = __builtin_amdgcn_mfma_f32_16x16x32_bf16(fr2[kt], bh, c2a, 0, 0, 0);
        }

        // h -> LDS (XOR-by-site swizzle keeps agg reads bank-spread)
        if (q < 2) {
            int site = wv * 4 + (t >> 1);
            int mm   = ((t & 1) << 4) + m;
            int mmS  = mm ^ (site & 3);
            bf16x4 o;
            o[0] = (__bf16)fmaxf(c2a[0] + c2b[0] + breg.x, 0.f);
            o[1] = (__bf16)fmaxf(c2a[1] + c2b[1] + breg.y, 0.f);
            o[2] = (__bf16)fmaxf(c2a[2] + c2b[2] + breg.z, 0.f);
            o[3] = (__bf16)fmaxf(c2a[3] + c2b[3] + breg.w, 0.f);
            *(bf16x4*)(sH + site * 256 + mmS * 8 + q * 4) = o;
        }
    }

    // wave 3 stages head bias/W4 into its (now dead) ring
    if (wv == 3) {
        float* sB3s = (float*)(smem + SB3_OFF);
        float* sW4s = (float*)(smem + SW4_OFF);
        for (int e = lane; e < 160; e += 64) {
            sB3s[e] = (e < HDIM) ? b3[e] : 0.f;
            sW4s[e] = (e < HDIM) ? W4[e] : 0.f;
        }
    }

    // ---- aggregation: 16 threads/site; no barrier needed (same-wave data) --
    {
        const int aS  = tid >> 4;          // site 0..15 (aS>>2 == wv)
        const int hf_ = (tid >> 3) & 1;    // half: reads 0..15 / 16..31
        const int p   = tid & 7;           // channel
        const int s2  = aS & 3;
        const __bf16* hp = sH + aS * 256 + p;

        float v[16];
        float sum = 0.f, sumsq = 0.f;
#pragma unroll
        for (int i = 0; i < 16; ++i) {
            float vv = (float)hp[((hf_ * 16 + i) ^ s2) * 8];
            v[i] = vv;
            sum += vv;
            sumsq = fmaf(vv, vv, sumsq);
        }
        sort16(v);

        // lower median of 32 = max_i min(a[i], b[15-i])  (bitonic halver)
        float med = -1e30f, mn = v[0], mx = v[15];
#pragma unroll
        for (int i = 0; i < 16; ++i) {
            float tp = __shfl_xor(v[15 - i], 8);   // partner's v[15-i]
            if (i == 0)  mx = fmaxf(v[15], tp);    // tp = partner max
            if (i == 15) mn = fminf(v[0], tp);     // tp = partner min
            med = fmaxf(med, fminf(v[i], tp));
        }
        float s1  = sum   + __shfl_xor(sum, 8);
        float ss1 = sumsq + __shfl_xor(sumsq, 8);
        float mean = s1 * (1.f / 32.f);
        float var  = fmaxf((ss1 - 32.f * mean * mean) * (1.f / 31.f), 0.f);

        if (!(tid & 8)) {   // half 0 writes this site's stats into own ring
            float* ab = (float*)(smem + (aS >> 2) * RING_B + (aS & 3) * 176);
            ab[0 * 8 + p] = mean;
            ab[1 * 8 + p] = var;
            ab[2 * 8 + p] = mn;
            ab[3 * 8 + p] = med;
            ab[4 * 8 + p] = mx;
        }
    }

    // head A-fragments (issued before the barrier to hide latency)
    const int njt = (wv < 2) ? 3 : 2;      // wave jt sets {0,4,8},{1,5,9},{2,6},{3,7}
    uint4 HF[6];
#pragma unroll
    for (int k2 = 0; k2 < 3; ++k2) {
        if (k2 < njt) {
            int jt = wv + 4 * k2;
            HF[k2 * 2 + 0] = bl[(16 + jt * 2 + 0) * 64 + lane];
            HF[k2 * 2 + 1] = bl[(16 + jt * 2 + 1) * 64 + lane];
        }
    }
    const bf16x8* hfr = (const bf16x8*)HF;
    __syncthreads();   // all AggW + b3/W4 staged visible

    // ---- head MLP via MFMA: Z[150x16] = W3^T @ AGG[40x16] ----
    // B-frag: lane(m,q) holds AGG[k = kc*32+q*8+j][site m], split bf16 hi/lo
    const float* ar = (const float*)(smem + (m >> 2) * RING_B + (m & 3) * 176);
    bf16x8 bh0, bl0, bh1, bl1;
    {
        float4 a0 = *(const float4*)(ar + q * 8);
        float4 a1 = *(const float4*)(ar + q * 8 + 4);
        float va[8] = {a0.x, a0.y, a0.z, a0.w, a1.x, a1.y, a1.z, a1.w};
#pragma unroll
        for (int j = 0; j < 8; ++j) {
            __bf16 hi = (__bf16)va[j];
            bh0[j] = hi;
            bl0[j] = (__bf16)(va[j] - (float)hi);
        }
    }
    if (q == 0) {       // kc=1 covers k = 32..39 (stat 4); other q are zero
        float4 a0 = *(const float4*)(ar + 32);
        float4 a1 = *(const float4*)(ar + 36);
        float va[8] = {a0.x, a0.y, a0.z, a0.w, a1.x, a1.y, a1.z, a1.w};
#pragma unroll
        for (int j = 0; j < 8; ++j) {
            __bf16 hi = (__bf16)va[j];
            bh1[j] = hi;
            bl1[j] = (__bf16)(va[j] - (float)hi);
        }
    } else {
#pragma unroll
        for (int j = 0; j < 8; ++j) { bh1[j] = (__bf16)0.f; bl1[j] = (__bf16)0.f; }
    }

    const float4* b3v = (const float4*)(smem + SB3_OFF);
    const float4* w4v = (const float4*)(smem + SW4_OFF);
    float sacc = 0.f;
#pragma unroll
    for (int k2 = 0; k2 < 3; ++k2) {
        if (k2 < njt) {
            int jt = wv + 4 * k2;
            float4 bi = b3v[jt * 4 + q];             // rows jt*16+q*4 .. +3
            f32x4 acc = {bi.x, bi.y, bi.z, bi.w};
            acc = __builtin_amdgcn_mfma_f32_16x16x32_bf16(hfr[k2 * 2 + 0], bh0, acc, 0, 0, 0);
            acc = __builtin_amdgcn_mfma_f32_16x16x32_bf16(hfr[k2 * 2 + 0], bl0, acc, 0, 0, 0);
            acc = __builtin_amdgcn_mfma_f32_16x16x32_bf16(hfr[k2 * 2 + 1], bh1, acc, 0, 0, 0);
            acc = __builtin_amdgcn_mfma_f32_16x16x32_bf16(hfr[k2 * 2 + 1], bl1, acc, 0, 0, 0);
            float4 w4q = w4v[jt * 4 + q];
            sacc = fmaf(fmaxf(acc[0], 0.f), w4q.x, sacc);
            sacc = fmaf(fmaxf(acc[1], 0.f), w4q.y, sacc);
            sacc = fmaf(fmaxf(acc[2], 0.f), w4q.z, sacc);
            sacc = fmaf(fmaxf(acc[3], 0.f), w4q.w, sacc);
        }
    }
    // reduce over the 4 q row-groups, then combine the 4 waves' jt partials
    sacc += __shfl_xor(sacc, 16);
    sacc += __shfl_xor(sacc, 32);
    if (lane < 16) ((float*)(smem + SPART_OFF))[wv * 16 + lane] = sacc;
    __syncthreads();
    if (tid < 16) {
        const float* sp = (const float*)(smem + SPART_OFF);
        float zf = sp[tid] + sp[16 + tid] + sp[32 + tid] + sp[48 + tid] + b4[0];
        if (gblk + tid < Gtot) out[gblk + tid] = 1.f / (1.f + expf(-zf));
    }
}

// ---------------------------------------------------------------------------
extern "C" void kernel_launch(void* const* d_in, const int* in_sizes, int n_in,
                              void* d_out, int out_size, void* d_ws, size_t ws_size,
                              hipStream_t stream) {
    const float* x       = (const float*)d_in[0];
    const int*   kmer    = (const int*)  d_in[1];
    const int*   indices = (const int*)  d_in[2];
    const float* emb     = (const float*)d_in[3];
    const float* W1      = (const float*)d_in[4];
    const float* b1      = (const float*)d_in[5];
    const float* W2      = (const float*)d_in[6];
    const float* b2      = (const float*)d_in[7];
    const float* W3      = (const float*)d_in[8];
    const float* b3      = (const float*)d_in[9];
    const float* W4      = (const float*)d_in[10];
    const float* b4      = (const float*)d_in[11];

    float* out = (float*)d_out;
    unsigned int* blob = (unsigned int*)d_ws;    // 36 KB fragment blob

    const int G = out_size;

    k_pack<<<1, 256, 0, stream>>>(W1, b1, W2, b2, W3, blob);

    const int grid = (G + 15) / 16;              // 16 sites / block
    k_fused<<<grid, 256, 0, stream>>>(x, kmer, indices, emb, blob,
                                      b3, W4, b4, out, G);
}

// Round 4
// 47.840 us; speedup vs baseline: 1.0050x; 1.0050x over previous
//
#include <hip/hip_runtime.h>
#include <hip/hip_bf16.h>
#include <math.h>

#define HDIM 150

typedef __bf16 bf16x8 __attribute__((ext_vector_type(8)));
typedef __bf16 bf16x4 __attribute__((ext_vector_type(4)));
typedef float  f32x4  __attribute__((ext_vector_type(4)));

__device__ __forceinline__ void async_copy16(const void* g, void* l) {
    __builtin_amdgcn_global_load_lds(
        (const __attribute__((address_space(1))) void*)g,
        (__attribute__((address_space(3))) void*)l, 16, 0, 0);
}

// ---------------------------------------------------------------------------
// k_pack: one block precomputes every per-lane MFMA fragment blob.
// Blob layout (uint4 view): tile i of lane L at blob4[i*64 + L].
//   tiles 0..9  : layer1 A-fragments
//   tiles 10..14: layer2 A-fragments -- R12: spare row k==150 carries b2
//                 (bias folded into the MFMA; k_fused supplies bh=1 there)
//   tile 15     : b2 floats (legacy, unused by k_fused)
//   tiles 16..35: head A-fragments  tile 16 + jt*2 + kc  =
//                 A[row = jt*16+m][k = kc*32+q*8+j] = W3[k][jt*16+m] (bf16)
// ---------------------------------------------------------------------------
__global__ void k_pack(const float* __restrict__ W1, const float* __restrict__ b1,
                       const float* __restrict__ W2, const float* __restrict__ b2,
                       const float* __restrict__ W3,
                       unsigned int* __restrict__ blob)
{
    __shared__ float sW[6000];   // phase1: W1|b1@2700|W2@2850 ; phase2: W3[40][150]

    const int t    = threadIdx.x;
    const int lane = t & 63;
    const int c    = t >> 6;        // dword chunk 0..3
    const int m    = lane & 15;
    const int q    = lane >> 4;

    for (int e = t; e < 2700; e += 256) sW[e] = W1[e];
    for (int e = t; e < 150;  e += 256) sW[2700 + e] = b1[e];
    for (int e = t; e < 1200; e += 256) sW[2850 + e] = W2[e];
    __syncthreads();

    for (int d = c * 16; d < c * 16 + 16; ++d) {
        unsigned int word;
        if (d >= 60) {
            word = __float_as_uint(b2[(q & 1) * 4 + (d - 60)]);
        } else {
            float v0 = 0.f, v1 = 0.f;
            if (d < 40) {
                int n = d >> 2, j0 = (d & 3) * 2;
                // permuted hidden rows for the register relay:
                //   tile 2kt   row(4q+r) = hidden 32kt+8q+r
                //   tile 2kt+1 row(4q+r) = hidden 32kt+8q+4+r
                int hid = 32 * (n >> 1) + 8 * (m >> 2) + 4 * (n & 1) + (m & 3);
                if (hid < HDIM) {
                    int k0 = q * 8 + j0, k1 = k0 + 1;
                    v0 = (k0 < 18) ? sW[k0 * HDIM + hid] : (k0 == 18 ? sW[2700 + hid] : 0.f);
                    v1 = (k1 < 18) ? sW[k1 * HDIM + hid] : (k1 == 18 ? sW[2700 + hid] : 0.f);
                }
            } else {
                int kt = (d - 40) >> 2, j0 = ((d - 40) & 3) * 2;
                int k0 = kt * 32 + q * 8 + j0, k1 = k0 + 1;
                if (m < 8) {
                    v0 = (k0 < HDIM) ? sW[2850 + k0 * 8 + m]
                                     : (k0 == HDIM ? b2[m] : 0.f);   // b2 row
                    v1 = (k1 < HDIM) ? sW[2850 + k1 * 8 + m]
                                     : (k1 == HDIM ? b2[m] : 0.f);
                }
            }
            __bf16 h0 = (__bf16)v0, h1 = (__bf16)v1;
            unsigned short u0, u1;
            __builtin_memcpy(&u0, &h0, 2);
            __builtin_memcpy(&u1, &h1, 2);
            word = (unsigned int)u0 | ((unsigned int)u1 << 16);
        }
        blob[(d >> 2) * 256 + lane * 4 + (d & 3)] = word;
    }
    __syncthreads();   // phase-1 reads of sW complete

    // ---- head A-fragments from W3 [40][150] row-major ----
    for (int e = t; e < 6000; e += 256) sW[e] = W3[e];
    __syncthreads();

    for (int f = t; f < 20 * 256; f += 256) {
        int tile  = f >> 8, rem = f & 255;
        int lane2 = rem >> 2, dw = rem & 3;
        int m2 = lane2 & 15, q2 = lane2 >> 4;
        int jt = tile >> 1, kc = tile & 1;
        int row = jt * 16 + m2;
        int k0  = kc * 32 + q2 * 8 + dw * 2;
        float v0 = (k0     < 40 && row < HDIM) ? sW[k0 * HDIM + row] : 0.f;
        float v1 = (k0 + 1 < 40 && row < HDIM) ? sW[(k0 + 1) * HDIM + row] : 0.f;
        __bf16 h0 = (__bf16)v0, h1 = (__bf16)v1;
        unsigned short u0, u1;
        __builtin_memcpy(&u0, &h0, 2);
        __builtin_memcpy(&u1, &h1, 2);
        blob[(16 + tile) * 256 + lane2 * 4 + dw] =
            (unsigned int)u0 | ((unsigned int)u1 << 16);
    }
}

// ---------------------------------------------------------------------------
// fully unrolled Batcher odd-even mergesort, n = 32
// ---------------------------------------------------------------------------
__device__ __forceinline__ void cswap(float& a, float& b) {
    float lo = fminf(a, b);
    float hi = fmaxf(a, b);
    a = lo; b = hi;
}

__device__ __forceinline__ void sort32(float v[32]) {
#pragma unroll
    for (int pp = 1; pp < 32; pp <<= 1) {
#pragma unroll
        for (int k = pp; k >= 1; k >>= 1) {
#pragma unroll
            for (int j = k & (pp - 1); j + k < 32; j += 2 * k) {
#pragma unroll
                for (int i = 0; i < k; ++i) {
                    if ((i + j) / (2 * pp) == (i + j + k) / (2 * pp))
                        cswap(v[i + j], v[i + j + k]);
                }
            }
        }
    }
}

// ---------------------------------------------------------------------------
// k_fused R12: R10 structure (32 sites/block, register-resident fragments)
// with two occupancy/latency levers:
//  * blob shrunk to 15 tiles (b2 folded into layer2 MFMA via spare k=150 row,
//    bh[6](q==2,kt==4) = 1.0): 60 AGPR + ~64 VGPR -> unified <= 128
//    -> 4 waves/SIMD (was 3 at 132 regs).
//  * x-gather pipeline deepened: 4 x 1KB ring per wave, prefetch 3 tiles
//    ahead, counted vmcnt(3) (covers ~800cyc of L3 gather latency vs ~275
//    at 1-deep).
// LDS: rings 16KB + sH 16.9KB = 33.3KB -> 4 blocks/CU. Ring region reused
// post-MLP for sB3/sW4/sAgg/sPart.
// ---------------------------------------------------------------------------
#define RING_B     4096                  // per wave: 4 buffers x 1 KB
#define SH_OFF     16384                 // sH: 32*264 bf16 = 16896 B
#define B3_OFF     0                     // float[160] (pad zeroed) = 640 B
#define W4_OFF     640                   // float[160]              = 640 B
#define AGG_OFF    1280                  // float[32*44]            = 5632 B
#define PART_OFF   6912                  // float[32]               = 128 B
#define SMEM_TOTAL (16384 + 16896)       // 33280 B -> 4 blocks/CU

__global__ __launch_bounds__(256, 4) void k_fused(
    const float* __restrict__ x, const int* __restrict__ kmer,
    const int* __restrict__ indices, const float* __restrict__ emb,
    const unsigned int* __restrict__ blob,
    const float* __restrict__ b3, const float* __restrict__ W4,
    const float* __restrict__ b4,
    float* __restrict__ out, int Gtot)
{
    __shared__ __align__(16) char smem[SMEM_TOTAL];

    const int tid  = threadIdx.x;
    const int lane = tid & 63;
    const int wv   = tid >> 6;
    const int m    = lane & 15;
    const int q    = lane >> 4;

    // ---- fragment blob: 15 coalesced dwordx4 loads (L2-hot) ----
    uint4 B16[15];
    const uint4* bl = (const uint4*)blob;
#pragma unroll
    for (int i = 0; i < 15; ++i) B16[i] = bl[i * 64 + lane];
    const bf16x8* fr = (const bf16x8*)B16;       // fr[0..9]=fA1, fr[10..14]=fA2

    const int gblk  = blockIdx.x * 32;           // first site of this block
    const int rbase = gblk * 32;                 // first flat read-slot

    // ---- per-wave read indices + emb for 4 64-read groups ----
    int    rg[4];
    float2 eg[4];
    {
        const int lim = Gtot * 32 - 1;
#pragma unroll
        for (int g = 0; g < 4; ++g) {
            int fl = rbase + wv * 256 + g * 64 + lane;
            rg[g] = indices[fl > lim ? lim : fl];
        }
        int kk[4];
#pragma unroll
        for (int g = 0; g < 4; ++g) kk[g] = kmer[rg[g]];
        const float2* emb2 = (const float2*)emb;
#pragma unroll
        for (int g = 0; g < 4; ++g) eg[g] = emb2[kk[g]];
    }

    char* xb = smem + wv * RING_B;
    const char* xg = (const char*)x;
    const int gsw = lane ^ ((lane >> 3) & 7);    // swizzled granule for DMA
    const int rsl = gsw >> 2;                    // read slot in tile (0..15)
    const int rch = gsw & 3;                     // 16B chunk in x row

    // ---- prologue: issue tiles 0..2 into ring slots 0..2 ----
#pragma unroll
    for (int t = 0; t < 3; ++t) {
        int rr = __shfl(rg[t >> 2], ((t & 3) << 4) + rsl);
        async_copy16(xg + (size_t)rr * 64 + (size_t)rch * 16, xb + (t << 10));
    }

    __bf16* sH = (__bf16*)(smem + SH_OFF);
    const f32x4 zero = {0.f, 0.f, 0.f, 0.f};

#pragma unroll
    for (int t = 0; t < 16; ++t) {
        // keep 3 tiles in flight; counted waits so only tile t must be ready
        if (t < 13) {
            int t3 = t + 3;
            int rr = __shfl(rg[t3 >> 2], ((t3 & 3) << 4) + rsl);
            async_copy16(xg + (size_t)rr * 64 + (size_t)rch * 16,
                         xb + ((t3 & 3) << 10));
            asm volatile("s_waitcnt vmcnt(3)" ::: "memory");
        } else if (t == 13) {
            asm volatile("s_waitcnt vmcnt(2)" ::: "memory");
        } else if (t == 14) {
            asm volatile("s_waitcnt vmcnt(1)" ::: "memory");
        } else {
            asm volatile("s_waitcnt vmcnt(0)" ::: "memory");
        }

        float ex = __shfl(eg[t >> 2].x, ((t & 3) << 4) + m);
        float ey = __shfl(eg[t >> 2].y, ((t & 3) << 4) + m);

        // input B-fragment: B[k = q*8+j][n = read m]
        bf16x8 bin;
        if (q < 2) {
            int g0 = 4 * m + 2 * q;
            int sx = (g0 >> 3) & 7;
            const char* tb = xb + ((t & 3) << 10);
            f32x4 u0 = *(const f32x4*)(tb + ((g0       ^ sx) << 4));
            f32x4 u1 = *(const f32x4*)(tb + (((g0 + 1) ^ sx) << 4));
            bin[0] = (__bf16)u0[0]; bin[1] = (__bf16)u0[1];
            bin[2] = (__bf16)u0[2]; bin[3] = (__bf16)u0[3];
            bin[4] = (__bf16)u1[0]; bin[5] = (__bf16)u1[1];
            bin[6] = (__bf16)u1[2]; bin[7] = (__bf16)u1[3];
        } else if (q == 2) {
            bin[0] = (__bf16)ex; bin[1] = (__bf16)ey;
            bin[2] = (__bf16)1.0f;   // bias-1 input at k==18
            bin[3] = (__bf16)0.f; bin[4] = (__bf16)0.f;
            bin[5] = (__bf16)0.f; bin[6] = (__bf16)0.f; bin[7] = (__bf16)0.f;
        } else {
#pragma unroll
            for (int j = 0; j < 8; ++j) bin[j] = (__bf16)0.f;
        }

        // layer1 tile-pair -> relu/pack -> layer2, all in registers.
        f32x4 c2a = zero, c2b = zero;
#pragma unroll
        for (int kt = 0; kt < 5; ++kt) {
            f32x4 ca = __builtin_amdgcn_mfma_f32_16x16x32_bf16(fr[2 * kt],     bin, zero, 0, 0, 0);
            f32x4 cb = __builtin_amdgcn_mfma_f32_16x16x32_bf16(fr[2 * kt + 1], bin, zero, 0, 0, 0);
            bf16x8 bh;
            bh[0] = (__bf16)fmaxf(ca[0], 0.f); bh[1] = (__bf16)fmaxf(ca[1], 0.f);
            bh[2] = (__bf16)fmaxf(ca[2], 0.f); bh[3] = (__bf16)fmaxf(ca[3], 0.f);
            bh[4] = (__bf16)fmaxf(cb[0], 0.f); bh[5] = (__bf16)fmaxf(cb[1], 0.f);
            bh[6] = (__bf16)fmaxf(cb[2], 0.f); bh[7] = (__bf16)fmaxf(cb[3], 0.f);
            if (kt == 4 && q == 2) bh[6] = (__bf16)1.0f;   // bias row k==150
            if (kt & 1) c2b = __builtin_amdgcn_mfma_f32_16x16x32_bf16(fr[10 + kt], bh, c2b, 0, 0, 0);
            else        c2a = __builtin_amdgcn_mfma_f32_16x16x32_bf16(fr[10 + kt], bh, c2a, 0, 0, 0);
        }

        // h -> LDS (never touches HBM); b2 already folded via bias row
        if (q < 2) {
            int br   = wv * 256 + t * 16 + m;    // block read idx
            int site = br >> 5, mm = br & 31;
            bf16x4 o;
            o[0] = (__bf16)fmaxf(c2a[0] + c2b[0], 0.f);
            o[1] = (__bf16)fmaxf(c2a[1] + c2b[1], 0.f);
            o[2] = (__bf16)fmaxf(c2a[2] + c2b[2], 0.f);
            o[3] = (__bf16)fmaxf(c2a[3] + c2b[3], 0.f);
            *(bf16x4*)(sH + site * 264 + mm * 8 + q * 4) = o;
        }
    }
    __syncthreads();   // all h in sH; DMA rings dead -> region reusable

    float* sB3  = (float*)(smem + B3_OFF);
    float* sW4  = (float*)(smem + W4_OFF);
    float* sAgg = (float*)(smem + AGG_OFF);
    float* sPart= (float*)(smem + PART_OFF);

    if (tid < 160) {
        sB3[tid] = (tid < HDIM) ? b3[tid] : 0.f;
        sW4[tid] = (tid < HDIM) ? W4[tid] : 0.f;
    }

    // ---- per-(site,p) aggregation: stats + sort for lower median ----
    const int sg = tid >> 3, p = tid & 7;
    {
        float v[32];
#pragma unroll
        for (int mm = 0; mm < 32; ++mm)
            v[mm] = (float)sH[sg * 264 + mm * 8 + p];

        float sum = 0.f, sumsq = 0.f, mn = v[0], mx = v[0];
#pragma unroll
        for (int mm = 0; mm < 32; ++mm) {
            sum += v[mm];
            sumsq = fmaf(v[mm], v[mm], sumsq);
            mn = fminf(mn, v[mm]);
            mx = fmaxf(mx, v[mm]);
        }
        float mean = sum * (1.f / 32.f);
        float var  = fmaxf((sumsq - 32.f * mean * mean) * (1.f / 31.f), 0.f);
        sort32(v);
        sAgg[sg * 44 + 0 * 8 + p] = mean;
        sAgg[sg * 44 + 1 * 8 + p] = var;
        sAgg[sg * 44 + 2 * 8 + p] = mn;
        sAgg[sg * 44 + 3 * 8 + p] = v[15];   // lower median
        sAgg[sg * 44 + 4 * 8 + p] = mx;
    }

    // ---- head A-fragments (loaded late; blob regs are dead by now) ----
    const int jthalf = wv >> 1, sh = wv & 1;
    uint4 HF[10];
#pragma unroll
    for (int i = 0; i < 10; ++i) {
        int jt = jthalf * 5 + (i >> 1), kc = i & 1;
        HF[i] = bl[(16 + jt * 2 + kc) * 64 + lane];
    }
    const bf16x8* hf = (const bf16x8*)HF;
    __syncthreads();   // all AggW + b3/W4 staged visible

    // ---- head MLP via MFMA: Z[j][site] = W3^T @ AGG, wave = (jthalf, sh) ----
    // B-frag: lane(m,q) holds AGG[k = kc*32+q*8+j][site sh*16+m], split hi/lo
    const int site = sh * 16 + m;
    const float* ar = sAgg + site * 44;
    bf16x8 bh0, bl0, bh1, bl1;
    {
        float4 a0 = *(const float4*)(ar + q * 8);
        float4 a1 = *(const float4*)(ar + q * 8 + 4);
        float va[8] = {a0.x, a0.y, a0.z, a0.w, a1.x, a1.y, a1.z, a1.w};
#pragma unroll
        for (int j = 0; j < 8; ++j) {
            __bf16 hi = (__bf16)va[j];
            bh0[j] = hi;
            bl0[j] = (__bf16)(va[j] - (float)hi);
        }
    }
    if (q == 0) {       // kc=1 covers k = 32..39 (stat 4); other q are zero
        float4 a0 = *(const float4*)(ar + 32);
        float4 a1 = *(const float4*)(ar + 36);
        float va[8] = {a0.x, a0.y, a0.z, a0.w, a1.x, a1.y, a1.z, a1.w};
#pragma unroll
        for (int j = 0; j < 8; ++j) {
            __bf16 hi = (__bf16)va[j];
            bh1[j] = hi;
            bl1[j] = (__bf16)(va[j] - (float)hi);
        }
    } else {
#pragma unroll
        for (int j = 0; j < 8; ++j) { bh1[j] = (__bf16)0.f; bl1[j] = (__bf16)0.f; }
    }

    const float4* b3v = (const float4*)sB3;
    const float4* w4v = (const float4*)sW4;
    float sacc = 0.f;
#pragma unroll
    for (int jj = 0; jj < 5; ++jj) {
        int jt = jthalf * 5 + jj;
        float4 bi = b3v[jt * 4 + q];             // rows jt*16+q*4 .. +3
        f32x4 acc = {bi.x, bi.y, bi.z, bi.w};
        acc = __builtin_amdgcn_mfma_f32_16x16x32_bf16(hf[jj * 2 + 0], bh0, acc, 0, 0, 0);
        acc = __builtin_amdgcn_mfma_f32_16x16x32_bf16(hf[jj * 2 + 0], bl0, acc, 0, 0, 0);
        acc = __builtin_amdgcn_mfma_f32_16x16x32_bf16(hf[jj * 2 + 1], bh1, acc, 0, 0, 0);
        acc = __builtin_amdgcn_mfma_f32_16x16x32_bf16(hf[jj * 2 + 1], bl1, acc, 0, 0, 0);
        float4 w4q = w4v[jt * 4 + q];
        sacc = fmaf(fmaxf(acc[0], 0.f), w4q.x, sacc);
        sacc = fmaf(fmaxf(acc[1], 0.f), w4q.y, sacc);
        sacc = fmaf(fmaxf(acc[2], 0.f), w4q.z, sacc);
        sacc = fmaf(fmaxf(acc[3], 0.f), w4q.w, sacc);
    }
    // reduce over the 4 q row-groups (j within tile), then across jthalf waves
    sacc += __shfl_xor(sacc, 16);
    sacc += __shfl_xor(sacc, 32);
    if (jthalf == 1 && lane < 16) sPart[sh * 16 + lane] = sacc;
    __syncthreads();
    if (jthalf == 0 && lane < 16) {
        int s2 = sh * 16 + lane;
        float zf = sacc + sPart[s2] + b4[0];
        if (gblk + s2 < Gtot) out[gblk + s2] = 1.f / (1.f + expf(-zf));
    }
}

// ---------------------------------------------------------------------------
extern "C" void kernel_launch(void* const* d_in, const int* in_sizes, int n_in,
                              void* d_out, int out_size, void* d_ws, size_t ws_size,
                              hipStream_t stream) {
    const float* x       = (const float*)d_in[0];
    const int*   kmer    = (const int*)  d_in[1];
    const int*   indices = (const int*)  d_in[2];
    const float* emb     = (const float*)d_in[3];
    const float* W1      = (const float*)d_in[4];
    const float* b1      = (const float*)d_in[5];
    const float* W2      = (const float*)d_in[6];
    const float* b2      = (const float*)d_in[7];
    const float* W3      = (const float*)d_in[8];
    const float* b3      = (const float*)d_in[9];
    const float* W4      = (const float*)d_in[10];
    const float* b4      = (const float*)d_in[11];

    float* out = (float*)d_out;
    unsigned int* blob = (unsigned int*)d_ws;    // 36 KB fragment blob

    const int G = out_size;

    k_pack<<<1, 256, 0, stream>>>(W1, b1, W2, b2, W3, blob);

    const int grid = (G + 31) / 32;              // 32 sites / block
    k_fused<<<grid, 256, 0, stream>>>(x, kmer, indices, emb, blob,
                                      b3, W4, b4, out, G);
}

// Round 5
// 47.079 us; speedup vs baseline: 1.0213x; 1.0162x over previous
//
#include <hip/hip_runtime.h>
#include <hip/hip_bf16.h>
#include <math.h>

#define HDIM 150

typedef __bf16 bf16x8 __attribute__((ext_vector_type(8)));
typedef __bf16 bf16x4 __attribute__((ext_vector_type(4)));
typedef float  f32x4  __attribute__((ext_vector_type(4)));

// ---------------------------------------------------------------------------
// k_pack: one block precomputes every per-lane MFMA fragment blob.
// Blob layout (uint4 view): tile i of lane L at blob4[i*64 + L].
//   tiles 0..9  : layer1 A-fragments
//   tiles 10..14: layer2 A-fragments -- spare row k==150 carries b2
//                 (bias folded into the MFMA; k_fused supplies bh=1 there)
//   tile 15     : b2 floats (legacy, unused by k_fused)
//   tiles 16..35: head A-fragments  tile 16 + jt*2 + kc  =
//                 A[row = jt*16+m][k = kc*32+q*8+j] = W3[k][jt*16+m] (bf16)
// ---------------------------------------------------------------------------
__global__ void k_pack(const float* __restrict__ W1, const float* __restrict__ b1,
                       const float* __restrict__ W2, const float* __restrict__ b2,
                       const float* __restrict__ W3,
                       unsigned int* __restrict__ blob)
{
    __shared__ float sW[6000];   // phase1: W1|b1@2700|W2@2850 ; phase2: W3[40][150]

    const int t    = threadIdx.x;
    const int lane = t & 63;
    const int c    = t >> 6;        // dword chunk 0..3
    const int m    = lane & 15;
    const int q    = lane >> 4;

    for (int e = t; e < 2700; e += 256) sW[e] = W1[e];
    for (int e = t; e < 150;  e += 256) sW[2700 + e] = b1[e];
    for (int e = t; e < 1200; e += 256) sW[2850 + e] = W2[e];
    __syncthreads();

    for (int d = c * 16; d < c * 16 + 16; ++d) {
        unsigned int word;
        if (d >= 60) {
            word = __float_as_uint(b2[(q & 1) * 4 + (d - 60)]);
        } else {
            float v0 = 0.f, v1 = 0.f;
            if (d < 40) {
                int n = d >> 2, j0 = (d & 3) * 2;
                // permuted hidden rows for the register relay:
                //   tile 2kt   row(4q+r) = hidden 32kt+8q+r
                //   tile 2kt+1 row(4q+r) = hidden 32kt+8q+4+r
                int hid = 32 * (n >> 1) + 8 * (m >> 2) + 4 * (n & 1) + (m & 3);
                if (hid < HDIM) {
                    int k0 = q * 8 + j0, k1 = k0 + 1;
                    v0 = (k0 < 18) ? sW[k0 * HDIM + hid] : (k0 == 18 ? sW[2700 + hid] : 0.f);
                    v1 = (k1 < 18) ? sW[k1 * HDIM + hid] : (k1 == 18 ? sW[2700 + hid] : 0.f);
                }
            } else {
                int kt = (d - 40) >> 2, j0 = ((d - 40) & 3) * 2;
                int k0 = kt * 32 + q * 8 + j0, k1 = k0 + 1;
                if (m < 8) {
                    v0 = (k0 < HDIM) ? sW[2850 + k0 * 8 + m]
                                     : (k0 == HDIM ? b2[m] : 0.f);   // b2 row
                    v1 = (k1 < HDIM) ? sW[2850 + k1 * 8 + m]
                                     : (k1 == HDIM ? b2[m] : 0.f);
                }
            }
            __bf16 h0 = (__bf16)v0, h1 = (__bf16)v1;
            unsigned short u0, u1;
            __builtin_memcpy(&u0, &h0, 2);
            __builtin_memcpy(&u1, &h1, 2);
            word = (unsigned int)u0 | ((unsigned int)u1 << 16);
        }
        blob[(d >> 2) * 256 + lane * 4 + (d & 3)] = word;
    }
    __syncthreads();   // phase-1 reads of sW complete

    // ---- head A-fragments from W3 [40][150] row-major ----
    for (int e = t; e < 6000; e += 256) sW[e] = W3[e];
    __syncthreads();

    for (int f = t; f < 20 * 256; f += 256) {
        int tile  = f >> 8, rem = f & 255;
        int lane2 = rem >> 2, dw = rem & 3;
        int m2 = lane2 & 15, q2 = lane2 >> 4;
        int jt = tile >> 1, kc = tile & 1;
        int row = jt * 16 + m2;
        int k0  = kc * 32 + q2 * 8 + dw * 2;
        float v0 = (k0     < 40 && row < HDIM) ? sW[k0 * HDIM + row] : 0.f;
        float v1 = (k0 + 1 < 40 && row < HDIM) ? sW[(k0 + 1) * HDIM + row] : 0.f;
        __bf16 h0 = (__bf16)v0, h1 = (__bf16)v1;
        unsigned short u0, u1;
        __builtin_memcpy(&u0, &h0, 2);
        __builtin_memcpy(&u1, &h1, 2);
        blob[(16 + tile) * 256 + lane2 * 4 + dw] =
            (unsigned int)u0 | ((unsigned int)u1 << 16);
    }
}

// ---------------------------------------------------------------------------
// fully unrolled Batcher odd-even mergesort, n = 16
// ---------------------------------------------------------------------------
__device__ __forceinline__ void cswap(float& a, float& b) {
    float lo = fminf(a, b);
    float hi = fmaxf(a, b);
    a = lo; b = hi;
}

__device__ __forceinline__ void sort16(float v[16]) {
#pragma unroll
    for (int pp = 1; pp < 16; pp <<= 1) {
#pragma unroll
        for (int k = pp; k >= 1; k >>= 1) {
#pragma unroll
            for (int j = k & (pp - 1); j + k < 16; j += 2 * k) {
#pragma unroll
                for (int i = 0; i < k; ++i) {
                    if ((i + j) / (2 * pp) == (i + j + k) / (2 * pp))
                        cswap(v[i + j], v[i + j + k]);
                }
            }
        }
    }
}

// ---------------------------------------------------------------------------
// k_fused R13: x gathered DIRECTLY into VGPRs (no LDS staging).
// Lane (m,q<2) of tile t needs exactly x[rr(t,m)][q*8 .. q*8+7] = 32
// contiguous bytes -> 2x global_load_dwordx4, software-pipelined 2 tiles
// deep. Deletes the DMA ring, vmcnt asm gates, per-tile ds_read_b128, the
// XOR swizzle math, and the post-MLP barrier (agg reads same-wave data
// only). LDS 33.3 -> 23.9 KB; one barrier before head MFMA, one before out.
//  * agg median: two sort16 + bitonic-halver merge (R11-verified identity
//    med32 = max_i min(a[i], b[15-i])) -- ~100 fewer VALU insts/thread.
//  * b2 stays folded into layer2 MFMA via spare k=150 row (R12).
// ---------------------------------------------------------------------------
#define SH_OFF     0                     // sH: 32*264 bf16 = 16896 B
#define B3_OFF     16896                 // float[160] (pad zeroed) = 640 B
#define W4_OFF     17536                 // float[160]              = 640 B
#define AGG_OFF    18176                 // float[32*44]            = 5632 B
#define PART_OFF   23808                 // float[32]               = 128 B
#define SMEM_TOTAL 23936

__global__ __launch_bounds__(256, 4) void k_fused(
    const float* __restrict__ x, const int* __restrict__ kmer,
    const int* __restrict__ indices, const float* __restrict__ emb,
    const unsigned int* __restrict__ blob,
    const float* __restrict__ b3, const float* __restrict__ W4,
    const float* __restrict__ b4,
    float* __restrict__ out, int Gtot)
{
    __shared__ __align__(16) char smem[SMEM_TOTAL];

    const int tid  = threadIdx.x;
    const int lane = tid & 63;
    const int wv   = tid >> 6;
    const int m    = lane & 15;
    const int q    = lane >> 4;

    // ---- fragment blob: 15 coalesced dwordx4 loads (L2-hot) ----
    uint4 B16[15];
    const uint4* bl = (const uint4*)blob;
#pragma unroll
    for (int i = 0; i < 15; ++i) B16[i] = bl[i * 64 + lane];
    const bf16x8* fr = (const bf16x8*)B16;       // fr[0..9]=fA1, fr[10..14]=fA2

    const int gblk  = blockIdx.x * 32;           // first site of this block
    const int rbase = gblk * 32;                 // first flat read-slot

    // ---- per-wave read indices + emb for 4 64-read groups ----
    int    rg[4];
    float2 eg[4];
    {
        const int lim = Gtot * 32 - 1;
#pragma unroll
        for (int g = 0; g < 4; ++g) {
            int fl = rbase + wv * 256 + g * 64 + lane;
            rg[g] = indices[fl > lim ? lim : fl];
        }
        int kk[4];
#pragma unroll
        for (int g = 0; g < 4; ++g) kk[g] = kmer[rg[g]];
        const float2* emb2 = (const float2*)emb;
#pragma unroll
        for (int g = 0; g < 4; ++g) eg[g] = emb2[kk[g]];
    }

    const char* xg = (const char*)x;

    // ---- 2-tile-deep register pipeline for the x gather ----
    f32x4 xa[2][2];
    auto issueTile = [&](int t) {
        int rr = __shfl(rg[t >> 2], ((t & 3) << 4) + m);
        if (q < 2) {
            const f32x4* src = (const f32x4*)(xg + (size_t)rr * 64 + (size_t)q * 32);
            xa[t & 1][0] = src[0];
            xa[t & 1][1] = src[1];
        }
    };
    issueTile(0);
    issueTile(1);

    __bf16* sH = (__bf16*)(smem + SH_OFF);
    const f32x4 zero = {0.f, 0.f, 0.f, 0.f};

#pragma unroll
    for (int t = 0; t < 16; ++t) {
        float ex = __shfl(eg[t >> 2].x, ((t & 3) << 4) + m);
        float ey = __shfl(eg[t >> 2].y, ((t & 3) << 4) + m);

        // input B-fragment: B[k = q*8+j][n = read m]
        bf16x8 bin;
        if (q < 2) {
            f32x4 u0 = xa[t & 1][0];
            f32x4 u1 = xa[t & 1][1];
            bin[0] = (__bf16)u0[0]; bin[1] = (__bf16)u0[1];
            bin[2] = (__bf16)u0[2]; bin[3] = (__bf16)u0[3];
            bin[4] = (__bf16)u1[0]; bin[5] = (__bf16)u1[1];
            bin[6] = (__bf16)u1[2]; bin[7] = (__bf16)u1[3];
        } else if (q == 2) {
            bin[0] = (__bf16)ex; bin[1] = (__bf16)ey;
            bin[2] = (__bf16)1.0f;   // bias-1 input at k==18
            bin[3] = (__bf16)0.f; bin[4] = (__bf16)0.f;
            bin[5] = (__bf16)0.f; bin[6] = (__bf16)0.f; bin[7] = (__bf16)0.f;
        } else {
#pragma unroll
            for (int j = 0; j < 8; ++j) bin[j] = (__bf16)0.f;
        }

        // refill this buffer slot with tile t+2 (loads overlap the MFMAs)
        if (t < 14) issueTile(t + 2);

        // layer1 tile-pair -> relu/pack -> layer2, all in registers.
        f32x4 c2a = zero, c2b = zero;
#pragma unroll
        for (int kt = 0; kt < 5; ++kt) {
            f32x4 ca = __builtin_amdgcn_mfma_f32_16x16x32_bf16(fr[2 * kt],     bin, zero, 0, 0, 0);
            f32x4 cb = __builtin_amdgcn_mfma_f32_16x16x32_bf16(fr[2 * kt + 1], bin, zero, 0, 0, 0);
            bf16x8 bh;
            bh[0] = (__bf16)fmaxf(ca[0], 0.f); bh[1] = (__bf16)fmaxf(ca[1], 0.f);
            bh[2] = (__bf16)fmaxf(ca[2], 0.f); bh[3] = (__bf16)fmaxf(ca[3], 0.f);
            bh[4] = (__bf16)fmaxf(cb[0], 0.f); bh[5] = (__bf16)fmaxf(cb[1], 0.f);
            bh[6] = (__bf16)fmaxf(cb[2], 0.f); bh[7] = (__bf16)fmaxf(cb[3], 0.f);
            if (kt == 4 && q == 2) bh[6] = (__bf16)1.0f;   // bias row k==150
            if (kt & 1) c2b = __builtin_amdgcn_mfma_f32_16x16x32_bf16(fr[10 + kt], bh, c2b, 0, 0, 0);
            else        c2a = __builtin_amdgcn_mfma_f32_16x16x32_bf16(fr[10 + kt], bh, c2a, 0, 0, 0);
        }

        // h -> LDS (never touches HBM); b2 already folded via bias row
        if (q < 2) {
            int br   = wv * 256 + t * 16 + m;    // block read idx
            int site = br >> 5, mm = br & 31;
            bf16x4 o;
            o[0] = (__bf16)fmaxf(c2a[0] + c2b[0], 0.f);
            o[1] = (__bf16)fmaxf(c2a[1] + c2b[1], 0.f);
            o[2] = (__bf16)fmaxf(c2a[2] + c2b[2], 0.f);
            o[3] = (__bf16)fmaxf(c2a[3] + c2b[3], 0.f);
            *(bf16x4*)(sH + site * 264 + mm * 8 + q * 4) = o;
        }
    }
    // NOTE: no barrier here -- each wave aggregates exactly the sites it
    // produced (sites wv*8..wv*8+7); lgkmcnt ordering covers the RAW.

    float* sB3  = (float*)(smem + B3_OFF);
    float* sW4  = (float*)(smem + W4_OFF);
    float* sAgg = (float*)(smem + AGG_OFF);
    float* sPart= (float*)(smem + PART_OFF);

    if (tid < 160) {
        sB3[tid] = (tid < HDIM) ? b3[tid] : 0.f;
        sW4[tid] = (tid < HDIM) ? W4[tid] : 0.f;
    }

    // ---- per-(site,p) aggregation: stats + sort16x2 + halver merge ----
    const int sg = tid >> 3, p = tid & 7;
    {
        float va[16], vb[16];
        float sum = 0.f, sumsq = 0.f;
#pragma unroll
        for (int mm = 0; mm < 16; ++mm) {
            float v1 = (float)sH[sg * 264 + mm * 8 + p];
            float v2 = (float)sH[sg * 264 + (16 + mm) * 8 + p];
            va[mm] = v1; vb[mm] = v2;
            sum += v1 + v2;
            sumsq = fmaf(v1, v1, sumsq);
            sumsq = fmaf(v2, v2, sumsq);
        }
        sort16(va);
        sort16(vb);
        float mn = fminf(va[0], vb[0]);
        float mx = fmaxf(va[15], vb[15]);
        // lower median of 32 = max_i min(a[i], b[15-i])  (bitonic halver)
        float med = fminf(va[0], vb[15]);
#pragma unroll
        for (int i = 1; i < 16; ++i) med = fmaxf(med, fminf(va[i], vb[15 - i]));
        float mean = sum * (1.f / 32.f);
        float var  = fmaxf((sumsq - 32.f * mean * mean) * (1.f / 31.f), 0.f);
        sAgg[sg * 44 + 0 * 8 + p] = mean;
        sAgg[sg * 44 + 1 * 8 + p] = var;
        sAgg[sg * 44 + 2 * 8 + p] = mn;
        sAgg[sg * 44 + 3 * 8 + p] = med;
        sAgg[sg * 44 + 4 * 8 + p] = mx;
    }

    // ---- head A-fragments (loaded late; blob regs are dead by now) ----
    const int jthalf = wv >> 1, sh = wv & 1;
    uint4 HF[10];
#pragma unroll
    for (int i = 0; i < 10; ++i) {
        int jt = jthalf * 5 + (i >> 1), kc = i & 1;
        HF[i] = bl[(16 + jt * 2 + kc) * 64 + lane];
    }
    const bf16x8* hf = (const bf16x8*)HF;
    __syncthreads();   // all sAgg + sB3/sW4 visible block-wide

    // ---- head MLP via MFMA: Z[j][site] = W3^T @ AGG, wave = (jthalf, sh) ----
    // B-frag: lane(m,q) holds AGG[k = kc*32+q*8+j][site sh*16+m], split hi/lo
    const int site = sh * 16 + m;
    const float* ar = sAgg + site * 44;
    bf16x8 bh0, bl0, bh1, bl1;
    {
        float4 a0 = *(const float4*)(ar + q * 8);
        float4 a1 = *(const float4*)(ar + q * 8 + 4);
        float va[8] = {a0.x, a0.y, a0.z, a0.w, a1.x, a1.y, a1.z, a1.w};
#pragma unroll
        for (int j = 0; j < 8; ++j) {
            __bf16 hi = (__bf16)va[j];
            bh0[j] = hi;
            bl0[j] = (__bf16)(va[j] - (float)hi);
        }
    }
    if (q == 0) {       // kc=1 covers k = 32..39 (stat 4); other q are zero
        float4 a0 = *(const float4*)(ar + 32);
        float4 a1 = *(const float4*)(ar + 36);
        float va[8] = {a0.x, a0.y, a0.z, a0.w, a1.x, a1.y, a1.z, a1.w};
#pragma unroll
        for (int j = 0; j < 8; ++j) {
            __bf16 hi = (__bf16)va[j];
            bh1[j] = hi;
            bl1[j] = (__bf16)(va[j] - (float)hi);
        }
    } else {
#pragma unroll
        for (int j = 0; j < 8; ++j) { bh1[j] = (__bf16)0.f; bl1[j] = (__bf16)0.f; }
    }

    const float4* b3v = (const float4*)sB3;
    const float4* w4v = (const float4*)sW4;
    float sacc = 0.f;
#pragma unroll
    for (int jj = 0; jj < 5; ++jj) {
        int jt = jthalf * 5 + jj;
        float4 bi = b3v[jt * 4 + q];             // rows jt*16+q*4 .. +3
        f32x4 acc = {bi.x, bi.y, bi.z, bi.w};
        acc = __builtin_amdgcn_mfma_f32_16x16x32_bf16(hf[jj * 2 + 0], bh0, acc, 0, 0, 0);
        acc = __builtin_amdgcn_mfma_f32_16x16x32_bf16(hf[jj * 2 + 0], bl0, acc, 0, 0, 0);
        acc = __builtin_amdgcn_mfma_f32_16x16x32_bf16(hf[jj * 2 + 1], bh1, acc, 0, 0, 0);
        acc = __builtin_amdgcn_mfma_f32_16x16x32_bf16(hf[jj * 2 + 1], bl1, acc, 0, 0, 0);
        float4 w4q = w4v[jt * 4 + q];
        sacc = fmaf(fmaxf(acc[0], 0.f), w4q.x, sacc);
        sacc = fmaf(fmaxf(acc[1], 0.f), w4q.y, sacc);
        sacc = fmaf(fmaxf(acc[2], 0.f), w4q.z, sacc);
        sacc = fmaf(fmaxf(acc[3], 0.f), w4q.w, sacc);
    }
    // reduce over the 4 q row-groups (j within tile), then across jthalf waves
    sacc += __shfl_xor(sacc, 16);
    sacc += __shfl_xor(sacc, 32);
    if (jthalf == 1 && lane < 16) sPart[sh * 16 + lane] = sacc;
    __syncthreads();
    if (jthalf == 0 && lane < 16) {
        int s2 = sh * 16 + lane;
        float zf = sacc + sPart[s2] + b4[0];
        if (gblk + s2 < Gtot) out[gblk + s2] = 1.f / (1.f + expf(-zf));
    }
}

// ---------------------------------------------------------------------------
extern "C" void kernel_launch(void* const* d_in, const int* in_sizes, int n_in,
                              void* d_out, int out_size, void* d_ws, size_t ws_size,
                              hipStream_t stream) {
    const float* x       = (const float*)d_in[0];
    const int*   kmer    = (const int*)  d_in[1];
    const int*   indices = (const int*)  d_in[2];
    const float* emb     = (const float*)d_in[3];
    const float* W1      = (const float*)d_in[4];
    const float* b1      = (const float*)d_in[5];
    const float* W2      = (const float*)d_in[6];
    const float* b2      = (const float*)d_in[7];
    const float* W3      = (const float*)d_in[8];
    const float* b3      = (const float*)d_in[9];
    const float* W4      = (const float*)d_in[10];
    const float* b4      = (const float*)d_in[11];

    float* out = (float*)d_out;
    unsigned int* blob = (unsigned int*)d_ws;    // 36 KB fragment blob

    const int G = out_size;

    k_pack<<<1, 256, 0, stream>>>(W1, b1, W2, b2, W3, blob);

    const int grid = (G + 31) / 32;              // 32 sites / block
    k_fused<<<grid, 256, 0, stream>>>(x, kmer, indices, emb, blob,
                                      b3, W4, b4, out, G);
}

// Round 6
// 46.734 us; speedup vs baseline: 1.0288x; 1.0074x over previous
//
#include <hip/hip_runtime.h>
#include <hip/hip_bf16.h>
#include <math.h>

#define HDIM 150

typedef __bf16 bf16x8 __attribute__((ext_vector_type(8)));
typedef __bf16 bf16x4 __attribute__((ext_vector_type(4)));
typedef float  f32x4  __attribute__((ext_vector_type(4)));

// ---------------------------------------------------------------------------
// fully unrolled Batcher odd-even mergesort, n = 16
// ---------------------------------------------------------------------------
__device__ __forceinline__ void cswap(float& a, float& b) {
    float lo = fminf(a, b);
    float hi = fmaxf(a, b);
    a = lo; b = hi;
}

__device__ __forceinline__ void sort16(float v[16]) {
#pragma unroll
    for (int pp = 1; pp < 16; pp <<= 1) {
#pragma unroll
        for (int k = pp; k >= 1; k >>= 1) {
#pragma unroll
            for (int j = k & (pp - 1); j + k < 16; j += 2 * k) {
#pragma unroll
                for (int i = 0; i < k; ++i) {
                    if ((i + j) / (2 * pp) == (i + j + k) / (2 * pp))
                        cswap(v[i + j], v[i + j + k]);
                }
            }
        }
    }
}

// ---------------------------------------------------------------------------
// k_all R14: SINGLE kernel. The per-lane MFMA fragment blob is built by each
// block in an LDS prologue (k_pack's math verbatim), eliminating the serial
// k_pack launch (+~4-6us of serial run + launch gap). Head W3 fragments are
// built post-aggregation from W3 staged into the then-dead sH region.
//
// LDS overlay (39424 B -> 4 blocks/CU):
//   R0 [0,24000): phase A = W1|b1@2700|W2@2850 staging (16.2KB)
//                 phase B = sH (32*264 bf16 = 16896 B)
//                 phase D = W3 staging (6000 f32 = 24000 B)
//   R1 [24064,39424): phase A = fragment blob (15 tiles x 1KB = 15360 B)
//                 phase C/D = sAgg@24064 | sB3@29696 | sW4@30336 | sPart@30976
//
// Phases/barriers:
//   stage W1/b1/W2 -> bar1 -> build frag blob -> bar2 -> lanes read blob ->
//   MLP (direct-VGPR x gather, 2-deep pipeline; h -> sH) -> bar3 ->
//   agg (same-wave sites; sort16x2 + bitonic-halver median) -> bar4 ->
//   stage W3/b3/W4 -> bar5 -> per-lane head frags from LDS -> head MFMA ->
//   bar6 -> out.
//   bar3 protects R1 (blob reads) vs sAgg writes; bar4 protects sH vs W3.
// ---------------------------------------------------------------------------
#define FB_OFF     24064                 // frag blob (phase A)
#define AGG_OFF    24064                 // float[32*44] = 5632 (phase C)
#define B3_OFF     29696                 // float[160]
#define W4_OFF     30336                 // float[160]
#define PART_OFF   30976                 // float[32]
#define SMEM_TOTAL 39424

__global__ __launch_bounds__(256, 4) void k_all(
    const float* __restrict__ x, const int* __restrict__ kmer,
    const int* __restrict__ indices, const float* __restrict__ emb,
    const float* __restrict__ W1, const float* __restrict__ b1,
    const float* __restrict__ W2, const float* __restrict__ b2,
    const float* __restrict__ W3, const float* __restrict__ b3,
    const float* __restrict__ W4, const float* __restrict__ b4,
    float* __restrict__ out, int Gtot)
{
    __shared__ __align__(16) char smem[SMEM_TOTAL];

    const int tid  = threadIdx.x;
    const int lane = tid & 63;
    const int wv   = tid >> 6;
    const int m    = lane & 15;
    const int q    = lane >> 4;

    const int gblk  = blockIdx.x * 32;           // first site of this block
    const int rbase = gblk * 32;                 // first flat read-slot

    // ---- per-wave read indices + emb (independent of weights; issue early)
    int          rg[4];
    unsigned int egp[4];                         // packed bf16 (ex,ey)
    {
        const int lim = Gtot * 32 - 1;
#pragma unroll
        for (int g = 0; g < 4; ++g) {
            int fl = rbase + wv * 256 + g * 64 + lane;
            rg[g] = indices[fl > lim ? lim : fl];
        }
        int kk[4];
#pragma unroll
        for (int g = 0; g < 4; ++g) kk[g] = kmer[rg[g]];
        const float2* emb2 = (const float2*)emb;
#pragma unroll
        for (int g = 0; g < 4; ++g) {
            float2 e = emb2[kk[g]];
            __bf16 bx = (__bf16)e.x, by = (__bf16)e.y;
            unsigned short ux, uy;
            __builtin_memcpy(&ux, &bx, 2);
            __builtin_memcpy(&uy, &by, 2);
            egp[g] = (unsigned int)ux | ((unsigned int)uy << 16);
        }
    }

    // ---- phase A: stage W1|b1|W2, build fragment blob in LDS ----
    float* sWgt = (float*)smem;                  // [0,16200) floats
    for (int e = tid; e < 2700; e += 256) sWgt[e] = W1[e];
    for (int e = tid; e < 150;  e += 256) sWgt[2700 + e] = b1[e];
    for (int e = tid; e < 1200; e += 256) sWgt[2850 + e] = W2[e];
    __syncthreads();                             // bar1

    unsigned int* fb = (unsigned int*)(smem + FB_OFF);
    {
        const int c = tid >> 6;                  // dword chunk 0..3
        for (int d = c * 15; d < c * 15 + 15; ++d) {
            float v0 = 0.f, v1 = 0.f;
            if (d < 40) {
                int n = d >> 2, j0 = (d & 3) * 2;
                // permuted hidden rows for the register relay:
                //   tile 2kt   row(4q+r) = hidden 32kt+8q+r
                //   tile 2kt+1 row(4q+r) = hidden 32kt+8q+4+r
                int hid = 32 * (n >> 1) + 8 * (m >> 2) + 4 * (n & 1) + (m & 3);
                if (hid < HDIM) {
                    int k0 = q * 8 + j0, k1 = k0 + 1;
                    v0 = (k0 < 18) ? sWgt[k0 * HDIM + hid] : (k0 == 18 ? sWgt[2700 + hid] : 0.f);
                    v1 = (k1 < 18) ? sWgt[k1 * HDIM + hid] : (k1 == 18 ? sWgt[2700 + hid] : 0.f);
                }
            } else {
                int kt = (d - 40) >> 2, j0 = ((d - 40) & 3) * 2;
                int k0 = kt * 32 + q * 8 + j0, k1 = k0 + 1;
                if (m < 8) {
                    v0 = (k0 < HDIM) ? sWgt[2850 + k0 * 8 + m]
                                     : (k0 == HDIM ? b2[m] : 0.f);   // b2 row
                    v1 = (k1 < HDIM) ? sWgt[2850 + k1 * 8 + m]
                                     : (k1 == HDIM ? b2[m] : 0.f);
                }
            }
            __bf16 h0 = (__bf16)v0, h1 = (__bf16)v1;
            unsigned short u0, u1;
            __builtin_memcpy(&u0, &h0, 2);
            __builtin_memcpy(&u1, &h1, 2);
            fb[(d >> 2) * 256 + lane * 4 + (d & 3)] =
                (unsigned int)u0 | ((unsigned int)u1 << 16);
        }
    }
    __syncthreads();                             // bar2

    // ---- lanes pull their 15 fragment uint4s into registers ----
    uint4 B16[15];
    const uint4* fb4 = (const uint4*)fb;
#pragma unroll
    for (int i = 0; i < 15; ++i) B16[i] = fb4[i * 64 + lane];
    const bf16x8* fr = (const bf16x8*)B16;       // fr[0..9]=fA1, fr[10..14]=fA2

    const char* xg = (const char*)x;

    // ---- 2-tile-deep register pipeline for the x gather ----
    f32x4 xa[2][2];
    auto issueTile = [&](int t) {
        int rr = __shfl(rg[t >> 2], ((t & 3) << 4) + m);
        if (q < 2) {
            const f32x4* src = (const f32x4*)(xg + (size_t)rr * 64 + (size_t)q * 32);
            xa[t & 1][0] = src[0];
            xa[t & 1][1] = src[1];
        }
    };
    issueTile(0);
    issueTile(1);

    __bf16* sH = (__bf16*)smem;                  // R0 reused: weights dead
    const f32x4 zero = {0.f, 0.f, 0.f, 0.f};

#pragma unroll
    for (int t = 0; t < 16; ++t) {
        unsigned int ew = __shfl((int)egp[t >> 2], ((t & 3) << 4) + m);

        // input B-fragment: B[k = q*8+j][n = read m]
        bf16x8 bin;
        if (q < 2) {
            f32x4 u0 = xa[t & 1][0];
            f32x4 u1 = xa[t & 1][1];
            bin[0] = (__bf16)u0[0]; bin[1] = (__bf16)u0[1];
            bin[2] = (__bf16)u0[2]; bin[3] = (__bf16)u0[3];
            bin[4] = (__bf16)u1[0]; bin[5] = (__bf16)u1[1];
            bin[6] = (__bf16)u1[2]; bin[7] = (__bf16)u1[3];
        } else if (q == 2) {
            unsigned short lo = (unsigned short)(ew & 0xffffu);
            unsigned short hi = (unsigned short)(ew >> 16);
            __bf16 bx, by;
            __builtin_memcpy(&bx, &lo, 2);
            __builtin_memcpy(&by, &hi, 2);
            bin[0] = bx; bin[1] = by;
            bin[2] = (__bf16)1.0f;   // bias-1 input at k==18
            bin[3] = (__bf16)0.f; bin[4] = (__bf16)0.f;
            bin[5] = (__bf16)0.f; bin[6] = (__bf16)0.f; bin[7] = (__bf16)0.f;
        } else {
#pragma unroll
            for (int j = 0; j < 8; ++j) bin[j] = (__bf16)0.f;
        }

        // refill this buffer slot with tile t+2 (loads overlap the MFMAs)
        if (t < 14) issueTile(t + 2);

        // layer1 tile-pair -> relu/pack -> layer2, all in registers.
        f32x4 c2a = zero, c2b = zero;
#pragma unroll
        for (int kt = 0; kt < 5; ++kt) {
            f32x4 ca = __builtin_amdgcn_mfma_f32_16x16x32_bf16(fr[2 * kt],     bin, zero, 0, 0, 0);
            f32x4 cb = __builtin_amdgcn_mfma_f32_16x16x32_bf16(fr[2 * kt + 1], bin, zero, 0, 0, 0);
            bf16x8 bh;
            bh[0] = (__bf16)fmaxf(ca[0], 0.f); bh[1] = (__bf16)fmaxf(ca[1], 0.f);
            bh[2] = (__bf16)fmaxf(ca[2], 0.f); bh[3] = (__bf16)fmaxf(ca[3], 0.f);
            bh[4] = (__bf16)fmaxf(cb[0], 0.f); bh[5] = (__bf16)fmaxf(cb[1], 0.f);
            bh[6] = (__bf16)fmaxf(cb[2], 0.f); bh[7] = (__bf16)fmaxf(cb[3], 0.f);
            if (kt == 4 && q == 2) bh[6] = (__bf16)1.0f;   // bias row k==150
            if (kt & 1) c2b = __builtin_amdgcn_mfma_f32_16x16x32_bf16(fr[10 + kt], bh, c2b, 0, 0, 0);
            else        c2a = __builtin_amdgcn_mfma_f32_16x16x32_bf16(fr[10 + kt], bh, c2a, 0, 0, 0);
        }

        // h -> LDS (never touches HBM); b2 folded via bias row
        if (q < 2) {
            int br   = wv * 256 + t * 16 + m;    // block read idx
            int site = br >> 5, mm = br & 31;
            bf16x4 o;
            o[0] = (__bf16)fmaxf(c2a[0] + c2b[0], 0.f);
            o[1] = (__bf16)fmaxf(c2a[1] + c2b[1], 0.f);
            o[2] = (__bf16)fmaxf(c2a[2] + c2b[2], 0.f);
            o[3] = (__bf16)fmaxf(c2a[3] + c2b[3], 0.f);
            *(bf16x4*)(sH + site * 264 + mm * 8 + q * 4) = o;
        }
    }
    __syncthreads();   // bar3: MLP done; R1 blob reads done -> sAgg reusable

    float* sAgg = (float*)(smem + AGG_OFF);
    float* sPart= (float*)(smem + PART_OFF);

    // ---- per-(site,p) aggregation: stats + sort16x2 + halver merge ----
    const int sg = tid >> 3, p = tid & 7;
    {
        float va[16], vb[16];
        float sum = 0.f, sumsq = 0.f;
#pragma unroll
        for (int mm = 0; mm < 16; ++mm) {
            float v1 = (float)sH[sg * 264 + mm * 8 + p];
            float v2 = (float)sH[sg * 264 + (16 + mm) * 8 + p];
            va[mm] = v1; vb[mm] = v2;
            sum += v1 + v2;
            sumsq = fmaf(v1, v1, sumsq);
            sumsq = fmaf(v2, v2, sumsq);
        }
        sort16(va);
        sort16(vb);
        float mn = fminf(va[0], vb[0]);
        float mx = fmaxf(va[15], vb[15]);
        // lower median of 32 = max_i min(a[i], b[15-i])  (bitonic halver)
        float med = fminf(va[0], vb[15]);
#pragma unroll
        for (int i = 1; i < 16; ++i) med = fmaxf(med, fminf(va[i], vb[15 - i]));
        float mean = sum * (1.f / 32.f);
        float var  = fmaxf((sumsq - 32.f * mean * mean) * (1.f / 31.f), 0.f);
        sAgg[sg * 44 + 0 * 8 + p] = mean;
        sAgg[sg * 44 + 1 * 8 + p] = var;
        sAgg[sg * 44 + 2 * 8 + p] = mn;
        sAgg[sg * 44 + 3 * 8 + p] = med;
        sAgg[sg * 44 + 4 * 8 + p] = mx;
    }
    __syncthreads();   // bar4: all sH reads done -> R0 reusable for W3

    // ---- phase D: stage W3 (+b3/W4), build per-lane head fragments ----
    float* sW3  = (float*)smem;                  // [0,24000) floats
    float* sB3  = (float*)(smem + B3_OFF);
    float* sW4  = (float*)(smem + W4_OFF);
    for (int e = tid; e < 6000; e += 256) sW3[e] = W3[e];
    if (tid < 160) {
        sB3[tid] = (tid < HDIM) ? b3[tid] : 0.f;
        sW4[tid] = (tid < HDIM) ? W4[tid] : 0.f;
    }
    __syncthreads();   // bar5

    // head A-fragment: tile (jt,kc): A[row=jt*16+m][k=kc*32+q*8+j] = W3[k][row]
    const int jthalf = wv >> 1, sh = wv & 1;
    uint4 HF[10];
#pragma unroll
    for (int i = 0; i < 10; ++i) {
        int jt = jthalf * 5 + (i >> 1), kc = i & 1;
        int row = jt * 16 + m;
        unsigned int w[4];
#pragma unroll
        for (int dw = 0; dw < 4; ++dw) {
            int k0 = kc * 32 + q * 8 + dw * 2, k1 = k0 + 1;
            float v0 = (k0 < 40 && row < HDIM) ? sW3[k0 * HDIM + row] : 0.f;
            float v1 = (k1 < 40 && row < HDIM) ? sW3[k1 * HDIM + row] : 0.f;
            __bf16 h0 = (__bf16)v0, h1 = (__bf16)v1;
            unsigned short u0, u1;
            __builtin_memcpy(&u0, &h0, 2);
            __builtin_memcpy(&u1, &h1, 2);
            w[dw] = (unsigned int)u0 | ((unsigned int)u1 << 16);
        }
        HF[i] = make_uint4(w[0], w[1], w[2], w[3]);
    }
    const bf16x8* hf = (const bf16x8*)HF;

    // ---- head MLP via MFMA: Z[j][site] = W3^T @ AGG, wave = (jthalf, sh) ----
    // B-frag: lane(m,q) holds AGG[k = kc*32+q*8+j][site sh*16+m], split hi/lo
    const int site = sh * 16 + m;
    const float* ar = sAgg + site * 44;
    bf16x8 bh0, bl0, bh1, bl1;
    {
        float4 a0 = *(const float4*)(ar + q * 8);
        float4 a1 = *(const float4*)(ar + q * 8 + 4);
        float va[8] = {a0.x, a0.y, a0.z, a0.w, a1.x, a1.y, a1.z, a1.w};
#pragma unroll
        for (int j = 0; j < 8; ++j) {
            __bf16 hi = (__bf16)va[j];
            bh0[j] = hi;
            bl0[j] = (__bf16)(va[j] - (float)hi);
        }
    }
    if (q == 0) {       // kc=1 covers k = 32..39 (stat 4); other q are zero
        float4 a0 = *(const float4*)(ar + 32);
        float4 a1 = *(const float4*)(ar + 36);
        float va[8] = {a0.x, a0.y, a0.z, a0.w, a1.x, a1.y, a1.z, a1.w};
#pragma unroll
        for (int j = 0; j < 8; ++j) {
            __bf16 hi = (__bf16)va[j];
            bh1[j] = hi;
            bl1[j] = (__bf16)(va[j] - (float)hi);
        }
    } else {
#pragma unroll
        for (int j = 0; j < 8; ++j) { bh1[j] = (__bf16)0.f; bl1[j] = (__bf16)0.f; }
    }

    const float4* b3v = (const float4*)sB3;
    const float4* w4v = (const float4*)sW4;
    float sacc = 0.f;
#pragma unroll
    for (int jj = 0; jj < 5; ++jj) {
        int jt = jthalf * 5 + jj;
        float4 bi = b3v[jt * 4 + q];             // rows jt*16+q*4 .. +3
        f32x4 acc = {bi.x, bi.y, bi.z, bi.w};
        acc = __builtin_amdgcn_mfma_f32_16x16x32_bf16(hf[jj * 2 + 0], bh0, acc, 0, 0, 0);
        acc = __builtin_amdgcn_mfma_f32_16x16x32_bf16(hf[jj * 2 + 0], bl0, acc, 0, 0, 0);
        acc = __builtin_amdgcn_mfma_f32_16x16x32_bf16(hf[jj * 2 + 1], bh1, acc, 0, 0, 0);
        acc = __builtin_amdgcn_mfma_f32_16x16x32_bf16(hf[jj * 2 + 1], bl1, acc, 0, 0, 0);
        float4 w4q = w4v[jt * 4 + q];
        sacc = fmaf(fmaxf(acc[0], 0.f), w4q.x, sacc);
        sacc = fmaf(fmaxf(acc[1], 0.f), w4q.y, sacc);
        sacc = fmaf(fmaxf(acc[2], 0.f), w4q.z, sacc);
        sacc = fmaf(fmaxf(acc[3], 0.f), w4q.w, sacc);
    }
    // reduce over the 4 q row-groups (j within tile), then across jthalf waves
    sacc += __shfl_xor(sacc, 16);
    sacc += __shfl_xor(sacc, 32);
    if (jthalf == 1 && lane < 16) sPart[sh * 16 + lane] = sacc;
    __syncthreads();   // bar6
    if (jthalf == 0 && lane < 16) {
        int s2 = sh * 16 + lane;
        float zf = sacc + sPart[s2] + b4[0];
        if (gblk + s2 < Gtot) out[gblk + s2] = 1.f / (1.f + expf(-zf));
    }
}

// ---------------------------------------------------------------------------
extern "C" void kernel_launch(void* const* d_in, const int* in_sizes, int n_in,
                              void* d_out, int out_size, void* d_ws, size_t ws_size,
                              hipStream_t stream) {
    const float* x       = (const float*)d_in[0];
    const int*   kmer    = (const int*)  d_in[1];
    const int*   indices = (const int*)  d_in[2];
    const float* emb     = (const float*)d_in[3];
    const float* W1      = (const float*)d_in[4];
    const float* b1      = (const float*)d_in[5];
    const float* W2      = (const float*)d_in[6];
    const float* b2      = (const float*)d_in[7];
    const float* W3      = (const float*)d_in[8];
    const float* b3      = (const float*)d_in[9];
    const float* W4      = (const float*)d_in[10];
    const float* b4      = (const float*)d_in[11];

    float* out = (float*)d_out;
    const int G = out_size;

    const int grid = (G + 31) / 32;              // 32 sites / block
    k_all<<<grid, 256, 0, stream>>>(x, kmer, indices, emb,
                                    W1, b1, W2, b2, W3, b3, W4, b4,
                                    out, G);
}